// Round 1
// baseline (28070.657 us; speedup 1.0000x reference)
//
#include <hip/hip_runtime.h>
#include <hip/hip_cooperative_groups.h>

namespace cg = cooperative_groups;

#define VV 128
#define HH 1024
#define BB 128
#define TT 512
#define G4 4096

typedef __attribute__((ext_vector_type(8))) short bf16x8;
typedef __attribute__((ext_vector_type(16))) float f32x16;

__device__ __forceinline__ short f2bf(float f) {
  unsigned u = __float_as_uint(f);
  u = (u + 0x7fffu + ((u >> 16) & 1u)) >> 16;
  return (short)u;
}

__device__ __forceinline__ float fsig(float x) {
  x = fminf(fmaxf(x, -30.f), 30.f);
  float e = __expf(-x);
  return 1.f / (1.f + e);
}
__device__ __forceinline__ float ftanh(float x) {
  x = fminf(fmaxf(x, -15.f), 15.f);
  float e = __expf(-2.f * x);
  return (1.f - e) / (1.f + e);
}

// ---------------- pre-kernels (run every launch; pure functions of inputs) ----------------

// x (B,T,V) f32 -> xbf [T][B][V] bf16 (time-major so each step's A-panel is contiguous)
__global__ void conv_x(const float* __restrict__ x, short* __restrict__ xbf) {
  const int n = TT * BB * VV;
  for (int i = blockIdx.x * blockDim.x + threadIdx.x; i < n; i += gridDim.x * blockDim.x) {
    int v = i & (VV - 1);
    int tb = i >> 7;            // / VV
    int r = tb & (BB - 1);
    int t = tb >> 7;            // / BB
    xbf[i] = f2bf(x[((size_t)r * TT + t) * VV + v]);
  }
}

// h (L,B,H) -> bf16 parity-1 state buffers; c (L,B,H) -> f32 c region of d_out (used as live cell state)
__global__ void init_state(const float* __restrict__ h, const float* __restrict__ c,
                           short* __restrict__ h0buf, short* __restrict__ h1buf,
                           float* __restrict__ out) {
  const int n = 2 * BB * HH;
  for (int i = blockIdx.x * blockDim.x + threadIdx.x; i < n; i += gridDim.x * blockDim.x) {
    int rj = i & (BB * HH - 1);
    short hb = f2bf(h[i]);
    if (i < BB * HH) h0buf[BB * HH + rj] = hb;
    else             h1buf[BB * HH + rj] = hb;
    out[(size_t)BB * TT * HH + (size_t)2 * BB * HH + i] = c[i];
  }
}

// Pack weights into per-CU, per-k-chunk, per-lane MFMA B-fragment streams (bf16).
// Stream layout: [cu][kc][lane][e]  (1 KB per kc). Lane l supplies B[k = kc*16 + (l>>5)*8 + e][col = l&31].
// col_local 0..31 = [i(8) | f(8) | g(8) | o(8)], unit u = col&7 -> global gate col = (col>>3)*H + cu*8 + u.
__global__ void pack_w(const float* __restrict__ Wx0, const float* __restrict__ Wh0,
                       const float* __restrict__ Wx1, const float* __restrict__ Wh1,
                       short* __restrict__ wp0, short* __restrict__ wp1) {
  const int n0 = 128 * 72 * 512;   // layer0: K = 128+1024 = 1152 -> 72 kc16
  const int n1 = 128 * 128 * 512;  // layer1: K = 2048 -> 128 kc16
  for (int i = blockIdx.x * blockDim.x + threadIdx.x; i < n0 + n1; i += gridDim.x * blockDim.x) {
    if (i < n0) {
      int cu = i / (72 * 512);
      int rem = i - cu * (72 * 512);
      int kc = rem >> 9, le = rem & 511;
      int lane = le >> 3, e = le & 7;
      int k = kc * 16 + ((lane >> 5) << 3) + e;
      int cl = lane & 31;
      int gcol = (cl >> 3) * HH + cu * 8 + (cl & 7);
      float f = (k < VV) ? Wx0[(size_t)k * G4 + gcol] : Wh0[(size_t)(k - VV) * G4 + gcol];
      wp0[i] = f2bf(f);
    } else {
      int j = i - n0;
      int cu = j >> 16;
      int rem = j & 65535;
      int kc = rem >> 9, le = rem & 511;
      int lane = le >> 3, e = le & 7;
      int k = kc * 16 + ((lane >> 5) << 3) + e;
      int cl = lane & 31;
      int gcol = (cl >> 3) * HH + cu * 8 + (cl & 7);
      float f = (k < HH) ? Wx1[(size_t)k * G4 + gcol] : Wh1[(size_t)(k - HH) * G4 + gcol];
      wp1[j] = f2bf(f);
    }
  }
}

__global__ void pack_b(const float* __restrict__ b0, const float* __restrict__ b1,
                       float* __restrict__ bp) {
  int i = blockIdx.x * blockDim.x + threadIdx.x;
  if (i < 2 * 128 * 32) {
    int l = i >> 12;
    int cu = (i >> 5) & 127;
    int cc = i & 31;
    const float* b = l ? b1 : b0;
    bp[i] = b[(cc >> 3) * HH + cu * 8 + (cc & 7)];
  }
}

// ---------------- persistent cooperative LSTM kernel ----------------

__device__ __forceinline__ void gemm_part(f32x16& acc, const short* __restrict__ pa,
                                          const short* pb, int nk) {
  #pragma unroll 8
  for (int kc = 0; kc < nk; ++kc) {
    bf16x8 a = *(const bf16x8*)(pa + kc * 16);   // A: row = lane&31, 8 consecutive k
    bf16x8 b = *(const bf16x8*)(pb + kc * 512);  // B stream: lane-linear 16B, conflict-free
    acc = __builtin_amdgcn_mfma_f32_32x32x16_bf16(a, b, acc, 0, 0, 0);
  }
}

__global__ void __launch_bounds__(256) lstm_main(const short* __restrict__ xbf,
    short* __restrict__ h0buf, short* __restrict__ h1buf,
    const short* __restrict__ wp0, const short* __restrict__ wp1,
    const float* __restrict__ bpack, float* __restrict__ out) {
  __shared__ short wlds[128 * 512];  // 128 KB: per-CU weight fragment stream, resident all steps
  cg::grid_group grid = cg::this_grid();
  const int blk = blockIdx.x;
  const int layer = blk >> 7;   // 0..127 -> layer0, 128..255 -> layer1
  const int cu = blk & 127;
  const int tid = threadIdx.x;
  const int lane = tid & 63;
  const int wave = tid >> 6;

  const int nkc = layer ? 128 : 72;
  const short* wsrc = layer ? (wp1 + (size_t)cu * 128 * 512) : (wp0 + (size_t)cu * 72 * 512);
  const int n16 = nkc * 64;
  for (int i = tid; i < n16; i += 256)
    ((int4*)wlds)[i] = ((const int4*)wsrc)[i];
  __syncthreads();

  const int col = lane & 31;                       // C/D col for 32x32 MFMA
  const float bias = bpack[layer * 4096 + cu * 32 + col];
  const int uu = col & 7;
  const bool ewlane = (col < 8);                   // i-gate lanes do the elementwise
  const int arow = wave * 32 + (lane & 31);        // wave owns rows [32w, 32w+32)
  const int koff = (lane >> 5) << 3;
  float* cbase = out + (size_t)BB * TT * HH + (size_t)2 * BB * HH + (size_t)layer * BB * HH;

  for (int p = 0; p <= TT; ++p) {
    const bool active = layer ? (p >= 1) : (p < TT);
    if (active) {
      const int t = layer ? (p - 1) : p;
      f32x16 acc;
      #pragma unroll
      for (int r = 0; r < 16; ++r) acc[r] = bias;
      if (layer == 0) {
        const short* xb = xbf + (size_t)t * BB * VV;
        const short* h0r = h0buf + (size_t)((p + 1) & 1) * BB * HH;  // h0[t-1]
        gemm_part(acc, xb + arow * VV + koff, wlds + lane * 8, 8);
        gemm_part(acc, h0r + arow * HH + koff, wlds + 8 * 512 + lane * 8, 64);
      } else {
        const short* h0c = h0buf + (size_t)((p + 1) & 1) * BB * HH;  // h0[t] (written phase p-1)
        const short* h1p = h1buf + (size_t)(p & 1) * BB * HH;        // h1[t-1]
        gemm_part(acc, h0c + arow * HH + koff, wlds + lane * 8, 64);
        gemm_part(acc, h1p + arow * HH + koff, wlds + 64 * 512 + lane * 8, 64);
      }
      short* hw = layer ? (h1buf + (size_t)((p + 1) & 1) * BB * HH)
                        : (h0buf + (size_t)(p & 1) * BB * HH);
      #pragma unroll
      for (int r = 0; r < 16; ++r) {
        float a0 = acc[r];
        float f_ = __shfl_xor(a0, 8);    // f gate (col+8)
        float g_ = __shfl_xor(a0, 16);   // g gate (col+16)
        float o_ = __shfl_xor(a0, 24);   // o gate (col+24)
        if (ewlane) {
          float iv = fsig(a0), fv = fsig(f_), gv = ftanh(g_), ov = fsig(o_);
          int grow = wave * 32 + (r & 3) + ((r >> 2) << 3) + ((lane >> 5) << 2);
          int gcol = cu * 8 + uu;
          size_t cidx = (size_t)grow * HH + gcol;
          float cold = cbase[cidx];
          float cnew = fv * cold + iv * gv;
          cbase[cidx] = cnew;                       // live cell state == c_f output region
          float hnew = ov * ftanh(cnew);
          hw[cidx] = f2bf(hnew);
          if (layer) out[((size_t)grow * TT + t) * HH + gcol] = hnew;   // outs[b][t][j]
          if (t == TT - 1)                                               // h_f
            out[(size_t)BB * TT * HH + (size_t)layer * BB * HH + cidx] = hnew;
        }
      }
    }
    grid.sync();
  }
}

// ---------------- host ----------------

extern "C" void kernel_launch(void* const* d_in, const int* in_sizes, int n_in,
                              void* d_out, int out_size, void* d_ws, size_t ws_size,
                              hipStream_t stream) {
  const float* x   = (const float*)d_in[0];
  const float* h   = (const float*)d_in[1];
  const float* c   = (const float*)d_in[2];
  const float* Wx0 = (const float*)d_in[3];
  const float* Wh0 = (const float*)d_in[4];
  const float* b0  = (const float*)d_in[5];
  const float* Wx1 = (const float*)d_in[6];
  const float* Wh1 = (const float*)d_in[7];
  const float* b1  = (const float*)d_in[8];
  float* out = (float*)d_out;

  char* ws = (char*)d_ws;
  short* xbf = (short*)ws;                          // 16,777,216 B : [T][B][V] bf16
  short* h0b = (short*)(ws + 16777216);             //    524,288 B : [2][B][H] bf16
  short* h1b = (short*)(ws + 17301504);             //    524,288 B
  short* wp0 = (short*)(ws + 17825792);             //  9,437,184 B : layer0 frag stream
  short* wp1 = (short*)(ws + 27262976);             // 16,777,216 B : layer1 frag stream
  float* bp  = (float*)(ws + 44040192);             //     32,768 B : packed biases

  hipLaunchKernelGGL(conv_x,     dim3(2048), dim3(256), 0, stream, x, xbf);
  hipLaunchKernelGGL(init_state, dim3(512),  dim3(256), 0, stream, h, c, h0b, h1b, out);
  hipLaunchKernelGGL(pack_w,     dim3(4096), dim3(256), 0, stream, Wx0, Wh0, Wx1, Wh1, wp0, wp1);
  hipLaunchKernelGGL(pack_b,     dim3(32),   dim3(256), 0, stream, b0, b1, bp);

  void* args[] = {(void*)&xbf, (void*)&h0b, (void*)&h1b, (void*)&wp0, (void*)&wp1,
                  (void*)&bp, (void*)&out};
  hipLaunchCooperativeKernel((void*)lstm_main, dim3(256), dim3(256), args, 0, stream);
}

// Round 3
// 20058.908 us; speedup vs baseline: 1.3994x; 1.3994x over previous
//
#include <hip/hip_runtime.h>

#define VV 128
#define HH 1024
#define BB 128
#define TT 512
#define G4 4096
#define BTH ((size_t)BB * TT * HH)

typedef __attribute__((ext_vector_type(8))) short bf16x8;
typedef __attribute__((ext_vector_type(16))) float f32x16;

__device__ __forceinline__ short f2bf(float f) {
  unsigned u = __float_as_uint(f);
  u = (u + 0x7fffu + ((u >> 16) & 1u)) >> 16;
  return (short)u;
}

__device__ __forceinline__ float fsig(float x) {
  x = fminf(fmaxf(x, -30.f), 30.f);
  float e = __expf(-x);
  return 1.f / (1.f + e);
}
__device__ __forceinline__ float ftanh(float x) {
  x = fminf(fmaxf(x, -15.f), 15.f);
  float e = __expf(-2.f * x);
  return (1.f - e) / (1.f + e);
}

// ---------------- pre-kernels ----------------

// x (B,T,V) f32 -> xbf [T][B][V] bf16
__global__ void conv_x(const float* __restrict__ x, short* __restrict__ xbf) {
  const int n = TT * BB * VV;
  for (int i = blockIdx.x * blockDim.x + threadIdx.x; i < n; i += gridDim.x * blockDim.x) {
    int v = i & (VV - 1);
    int tb = i >> 7;
    int r = tb & (BB - 1);
    int t = tb >> 7;
    xbf[i] = f2bf(x[((size_t)r * TT + t) * VV + v]);
  }
}

// h (L,B,H) -> bf16 parity-1 state buffers
__global__ void init_state(const float* __restrict__ h,
                           short* __restrict__ h0buf, short* __restrict__ h1buf) {
  const int n = 2 * BB * HH;
  for (int i = blockIdx.x * blockDim.x + threadIdx.x; i < n; i += gridDim.x * blockDim.x) {
    int rj = i & (BB * HH - 1);
    short hb = f2bf(h[i]);
    if (i < BB * HH) h0buf[BB * HH + rj] = hb;
    else             h1buf[BB * HH + rj] = hb;
  }
}

// Pack weights into per-CU per-kc per-lane MFMA B-fragment streams (bf16).
__global__ void pack_w(const float* __restrict__ Wx0, const float* __restrict__ Wh0,
                       const float* __restrict__ Wx1, const float* __restrict__ Wh1,
                       short* __restrict__ wp0, short* __restrict__ wp1) {
  const int n0 = 128 * 72 * 512;
  const int n1 = 128 * 128 * 512;
  for (int i = blockIdx.x * blockDim.x + threadIdx.x; i < n0 + n1; i += gridDim.x * blockDim.x) {
    if (i < n0) {
      int cu = i / (72 * 512);
      int rem = i - cu * (72 * 512);
      int kc = rem >> 9, le = rem & 511;
      int lane = le >> 3, e = le & 7;
      int k = kc * 16 + ((lane >> 5) << 3) + e;
      int cl = lane & 31;
      int gcol = (cl >> 3) * HH + cu * 8 + (cl & 7);
      float f = (k < VV) ? Wx0[(size_t)k * G4 + gcol] : Wh0[(size_t)(k - VV) * G4 + gcol];
      wp0[i] = f2bf(f);
    } else {
      int j = i - n0;
      int cu = j >> 16;
      int rem = j & 65535;
      int kc = rem >> 9, le = rem & 511;
      int lane = le >> 3, e = le & 7;
      int k = kc * 16 + ((lane >> 5) << 3) + e;
      int cl = lane & 31;
      int gcol = (cl >> 3) * HH + cu * 8 + (cl & 7);
      float f = (k < HH) ? Wx1[(size_t)k * G4 + gcol] : Wh1[(size_t)(k - HH) * G4 + gcol];
      wp1[j] = f2bf(f);
    }
  }
}

__global__ void pack_b(const float* __restrict__ b0, const float* __restrict__ b1,
                       float* __restrict__ bp, unsigned* __restrict__ slots) {
  int i = blockIdx.x * blockDim.x + threadIdx.x;
  if (i < 2 * 128 * 32) {
    int l = i >> 12;
    int cu = (i >> 5) & 127;
    int cc = i & 31;
    const float* b = l ? b1 : b0;
    bp[i] = b[(cc >> 3) * HH + cu * 8 + (cc & 7)];
  }
  if (i < 256) slots[i] = 0u;   // barrier slots: re-armed every launch/replay
}

// ---------------- persistent LSTM kernel ----------------

template <int NK>
__device__ __forceinline__ void gemmN(f32x16* acc, const short* __restrict__ pa,
                                      const short* __restrict__ pb) {
  #pragma unroll 16
  for (int kc = 0; kc < NK; ++kc) {      // NK compile-time, 16|NK or NK<16: no remainder,
    bf16x8 a = *(const bf16x8*)(pa + kc * 16);   // kc&3 always static -> acc stays in regs
    bf16x8 b = *(const bf16x8*)(pb + kc * 512);
    acc[kc & 3] = __builtin_amdgcn_mfma_f32_32x32x16_bf16(a, b, acc[kc & 3], 0, 0, 0);
  }
}

__global__ void __launch_bounds__(256) lstm_main(const short* __restrict__ xbf,
    short* __restrict__ h0buf, short* __restrict__ h1buf,
    const short* __restrict__ wp0, const short* __restrict__ wp1,
    const float* __restrict__ bpack, const float* __restrict__ cin,
    float* __restrict__ out, unsigned* __restrict__ slots) {
  __shared__ short wlds[128 * 512];  // 128 KB weight fragment stream -> 1 block/CU, all co-resident
  const int blk = blockIdx.x;
  const int layer = blk >> 7;
  const int cu = blk & 127;
  const int tid = threadIdx.x;
  const int lane = tid & 63;
  const int wave = tid >> 6;

  const int nkc = layer ? 128 : 72;
  const short* wsrc = layer ? (wp1 + (size_t)cu * 128 * 512) : (wp0 + (size_t)cu * 72 * 512);
  const int n16 = nkc * 64;
  for (int i = tid; i < n16; i += 256)
    ((int4*)wlds)[i] = ((const int4*)wsrc)[i];
  __syncthreads();

  const int col = lane & 31;
  const float bias = bpack[layer * 4096 + cu * 32 + col];
  const int uu = col & 7;
  const bool ewlane = (col < 8);
  const int gcol = cu * 8 + uu;
  const int hi4 = ((lane >> 5) << 2);
  const int arow = wave * 32 + col;
  const int koff = (lane >> 5) << 3;

  // cell state lives in registers for the whole sequence
  float creg[16];
  #pragma unroll
  for (int r = 0; r < 16; ++r) {
    int grow = wave * 32 + (r & 3) + ((r >> 2) << 3) + hi4;
    creg[r] = ewlane ? cin[(size_t)layer * BB * HH + (size_t)grow * HH + gcol] : 0.f;
  }

  for (int p = 0; p <= TT; ++p) {
    const bool active = layer ? (p >= 1) : (p < TT);
    if (active) {
      const int t = layer ? (p - 1) : p;
      f32x16 acc[4];
      #pragma unroll
      for (int r = 0; r < 16; ++r) {
        acc[0][r] = bias; acc[1][r] = 0.f; acc[2][r] = 0.f; acc[3][r] = 0.f;
      }
      if (layer == 0) {
        gemmN<8>(acc, xbf + (size_t)t * BB * VV + (size_t)arow * VV + koff,
                 wlds + lane * 8);
        gemmN<64>(acc, h0buf + (size_t)((p + 1) & 1) * BB * HH + (size_t)arow * HH + koff,
                  wlds + 8 * 512 + lane * 8);
      } else {
        gemmN<64>(acc, h0buf + (size_t)((p + 1) & 1) * BB * HH + (size_t)arow * HH + koff,
                  wlds + lane * 8);
        gemmN<64>(acc, h1buf + (size_t)(p & 1) * BB * HH + (size_t)arow * HH + koff,
                  wlds + 64 * 512 + lane * 8);
      }
      f32x16 accf = (acc[0] + acc[1]) + (acc[2] + acc[3]);
      short* hw = layer ? (h1buf + (size_t)((p + 1) & 1) * BB * HH)
                        : (h0buf + (size_t)(p & 1) * BB * HH);
      #pragma unroll
      for (int r = 0; r < 16; ++r) {
        float a0 = accf[r];
        float f_ = __shfl_xor(a0, 8);
        float g_ = __shfl_xor(a0, 16);
        float o_ = __shfl_xor(a0, 24);
        const int grow = wave * 32 + (r & 3) + ((r >> 2) << 3) + hi4;
        float hnew = 0.f;
        if (ewlane) {
          float iv = fsig(a0), fv = fsig(f_), gv = ftanh(g_), ov = fsig(o_);
          float cnew = fv * creg[r] + iv * gv;
          creg[r] = cnew;
          hnew = ov * ftanh(cnew);
        }
        unsigned hb = (unsigned short)f2bf(hnew);
        unsigned pb2 = (unsigned)__shfl_xor((int)hb, 1);
        if (ewlane) {
          if (layer) out[(size_t)grow * TT * HH + (size_t)t * HH + gcol] = hnew;
          if (t == TT - 1) {
            out[BTH + (size_t)layer * BB * HH + (size_t)grow * HH + gcol] = hnew;          // h_f
            out[BTH + (size_t)(2 + layer) * BB * HH + (size_t)grow * HH + gcol] = creg[r]; // c_f
          }
          if (!(uu & 1)) {
            unsigned dw = hb | (pb2 << 16);
            *(unsigned*)(hw + (size_t)grow * HH + gcol) = dw;   // plain store; fence flushes
          }
        }
      }
    }
    if (p == TT) break;   // nothing after the last phase

    // ---- global barrier over the 256 co-resident blocks ----
    __syncthreads();                 // every wave's stores drained (vmcnt0) -> in L2
    if (tid < 64) {
      __threadfence();               // release: wbl2 sc1 -> whole-XCD L2 to coherent point
      if (tid == 0)
        __hip_atomic_store(&slots[blk], (unsigned)(p + 1),
                           __ATOMIC_RELAXED, __HIP_MEMORY_SCOPE_AGENT);
      const unsigned tgt = (unsigned)(p + 1);
      for (;;) {
        bool ok = true;
        #pragma unroll
        for (int j = 0; j < 4; ++j) {
          unsigned v = __hip_atomic_load(&slots[(tid << 2) + j],
                                         __ATOMIC_RELAXED, __HIP_MEMORY_SCOPE_AGENT);
          ok &= (v >= tgt);
        }
        if (__all(ok)) break;
        __builtin_amdgcn_s_sleep(2);
      }
      __threadfence();               // acquire: buffer_inv sc1 -> drop stale L1/L2 lines
    }
    __syncthreads();                 // hold other waves until inv complete
  }
}

// ---------------- host ----------------

extern "C" void kernel_launch(void* const* d_in, const int* in_sizes, int n_in,
                              void* d_out, int out_size, void* d_ws, size_t ws_size,
                              hipStream_t stream) {
  const float* x   = (const float*)d_in[0];
  const float* h   = (const float*)d_in[1];
  const float* c   = (const float*)d_in[2];
  const float* Wx0 = (const float*)d_in[3];
  const float* Wh0 = (const float*)d_in[4];
  const float* b0  = (const float*)d_in[5];
  const float* Wx1 = (const float*)d_in[6];
  const float* Wh1 = (const float*)d_in[7];
  const float* b1  = (const float*)d_in[8];
  float* out = (float*)d_out;

  char* ws = (char*)d_ws;
  short* xbf = (short*)ws;                          // 16,777,216 B
  short* h0b = (short*)(ws + 16777216);             //    524,288 B
  short* h1b = (short*)(ws + 17301504);             //    524,288 B
  short* wp0 = (short*)(ws + 17825792);             //  9,437,184 B
  short* wp1 = (short*)(ws + 27262976);             // 16,777,216 B
  float* bp  = (float*)(ws + 44040192);             //     32,768 B
  unsigned* slots = (unsigned*)(ws + 44072960);     //      1,024 B

  hipLaunchKernelGGL(conv_x,     dim3(2048), dim3(256), 0, stream, x, xbf);
  hipLaunchKernelGGL(init_state, dim3(512),  dim3(256), 0, stream, h, h0b, h1b);
  hipLaunchKernelGGL(pack_w,     dim3(4096), dim3(256), 0, stream, Wx0, Wh0, Wx1, Wh1, wp0, wp1);
  hipLaunchKernelGGL(pack_b,     dim3(32),   dim3(256), 0, stream, b0, b1, bp, slots);

  // 256 blocks x 1 block/CU (128 KB LDS) on 256 CUs: all co-resident under a
  // normal launch; custom slot barrier replaces cooperative grid.sync.
  hipLaunchKernelGGL(lstm_main, dim3(256), dim3(256), 0, stream,
                     xbf, h0b, h1b, wp0, wp1, bp, c, out, slots);
}

// Round 4
// 7809.026 us; speedup vs baseline: 3.5946x; 2.5687x over previous
//
#include <hip/hip_runtime.h>

#define VV 128
#define HH 1024
#define BB 128
#define TT 512
#define G4 4096
#define BTH ((size_t)BB * TT * HH)
#define HPAR (4 * 64 * 512)   // shorts per parity of an h fragment-stream buffer (256 KB)

typedef __attribute__((ext_vector_type(8))) short bf16x8;
typedef __attribute__((ext_vector_type(16))) float f32x16;

__device__ __forceinline__ short f2bf(float f) {
  unsigned u = __float_as_uint(f);
  u = (u + 0x7fffu + ((u >> 16) & 1u)) >> 16;
  return (short)u;
}

__device__ __forceinline__ float fsig(float x) {
  x = fminf(fmaxf(x, -30.f), 30.f);
  float e = __expf(-x);
  return 1.f / (1.f + e);
}
__device__ __forceinline__ float ftanh(float x) {
  x = fminf(fmaxf(x, -15.f), 15.f);
  float e = __expf(-2.f * x);
  return (1.f - e) / (1.f + e);
}

// ---------------- pre-kernels ----------------

// x (B,T,V) f32 -> xp fragment stream [t][rb(4)][kc(8)][lane(64)][e(8)] bf16
__global__ void conv_x(const float* __restrict__ x, short* __restrict__ xp) {
  const int n = TT * 4 * 8 * 512;
  for (int i = blockIdx.x * blockDim.x + threadIdx.x; i < n; i += gridDim.x * blockDim.x) {
    int e = i & 7, lane = (i >> 3) & 63, kc = (i >> 9) & 7, rb = (i >> 12) & 3, t = i >> 14;
    int row = rb * 32 + (lane & 31);
    int v = kc * 16 + ((lane >> 5) << 3) + e;
    xp[i] = f2bf(x[((size_t)row * TT + t) * VV + v]);
  }
}

// h (L,B,H) -> parity-1 fragment-stream state buffers
__global__ void init_state(const float* __restrict__ h,
                           short* __restrict__ h0p, short* __restrict__ h1p) {
  const int n = 2 * HPAR;
  for (int i = blockIdx.x * blockDim.x + threadIdx.x; i < n; i += gridDim.x * blockDim.x) {
    int inner = i & (HPAR - 1);
    int l = i >> 17;
    int e = i & 7, lane = (i >> 3) & 63, kc = (i >> 9) & 63, rb = (i >> 15) & 3;
    int row = rb * 32 + (lane & 31);
    int j = kc * 16 + ((lane >> 5) << 3) + e;
    short hb = f2bf(h[((size_t)l * BB + row) * HH + j]);
    (l ? h1p : h0p)[HPAR + inner] = hb;
  }
}

// Pack weights into per-CU per-kc per-lane MFMA B-fragment streams (bf16).
__global__ void pack_w(const float* __restrict__ Wx0, const float* __restrict__ Wh0,
                       const float* __restrict__ Wx1, const float* __restrict__ Wh1,
                       short* __restrict__ wp0, short* __restrict__ wp1) {
  const int n0 = 128 * 72 * 512;
  const int n1 = 128 * 128 * 512;
  for (int i = blockIdx.x * blockDim.x + threadIdx.x; i < n0 + n1; i += gridDim.x * blockDim.x) {
    if (i < n0) {
      int cu = i / (72 * 512);
      int rem = i - cu * (72 * 512);
      int kc = rem >> 9, le = rem & 511;
      int lane = le >> 3, e = le & 7;
      int k = kc * 16 + ((lane >> 5) << 3) + e;
      int cl = lane & 31;
      int gcol = (cl >> 3) * HH + cu * 8 + (cl & 7);
      float f = (k < VV) ? Wx0[(size_t)k * G4 + gcol] : Wh0[(size_t)(k - VV) * G4 + gcol];
      wp0[i] = f2bf(f);
    } else {
      int j = i - n0;
      int cu = j >> 16;
      int rem = j & 65535;
      int kc = rem >> 9, le = rem & 511;
      int lane = le >> 3, e = le & 7;
      int k = kc * 16 + ((lane >> 5) << 3) + e;
      int cl = lane & 31;
      int gcol = (cl >> 3) * HH + cu * 8 + (cl & 7);
      float f = (k < HH) ? Wx1[(size_t)k * G4 + gcol] : Wh1[(size_t)(k - HH) * G4 + gcol];
      wp1[j] = f2bf(f);
    }
  }
}

__global__ void pack_b(const float* __restrict__ b0, const float* __restrict__ b1,
                       float* __restrict__ bp, unsigned* __restrict__ slots) {
  int i = blockIdx.x * blockDim.x + threadIdx.x;
  if (i < 2 * 128 * 32) {
    int l = i >> 12;
    int cu = (i >> 5) & 127;
    int cc = i & 31;
    const float* b = l ? b1 : b0;
    bp[i] = b[(cc >> 3) * HH + cu * 8 + (cc & 7)];
  }
  if (i < 256) slots[i] = 0u;   // barrier slots re-armed every launch/replay
}

// ---------------- persistent LSTM kernel ----------------

// x GEMM: plain cacheable loads (x is read-only, precomputed)
template <int NK>
__device__ __forceinline__ void gemm_plain(f32x16* acc, const short* __restrict__ pa,
                                           const short* __restrict__ pb) {
  #pragma unroll
  for (int kc = 0; kc < NK; ++kc) {
    bf16x8 a = *(const bf16x8*)(pa + kc * 512);
    bf16x8 b = *(const bf16x8*)(pb + kc * 512);
    acc[kc & 3] = __builtin_amdgcn_mfma_f32_32x32x16_bf16(a, b, acc[kc & 3], 0, 0, 0);
  }
}

// h GEMM: coherent (sc0 sc1) asm loads, depth-2 pipelined 16-chunks, counted vmcnt.
__device__ __forceinline__ void gemm64_coh(f32x16* acc, const short* pa,
                                           const short* __restrict__ pb) {
  bf16x8 A0[16], A1[16];
  #pragma unroll
  for (int j = 0; j < 16; ++j)
    asm volatile("global_load_dwordx4 %0, %1, off sc0 sc1"
                 : "=v"(A0[j]) : "v"(pa + j * 512));
  #pragma unroll
  for (int c = 0; c < 4; ++c) {
    bf16x8* CUR = (c & 1) ? A1 : A0;
    bf16x8* NXT = (c & 1) ? A0 : A1;
    if (c < 3) {
      #pragma unroll
      for (int j = 0; j < 16; ++j)
        asm volatile("global_load_dwordx4 %0, %1, off sc0 sc1"
                     : "=v"(NXT[j]) : "v"(pa + (c + 1) * 16 * 512 + j * 512));
      asm volatile("s_waitcnt vmcnt(16)" ::: "memory");
    } else {
      asm volatile("s_waitcnt vmcnt(0)" ::: "memory");
    }
    #pragma unroll
    for (int j = 0; j < 16; ++j)
      asm volatile("" : "+v"(CUR[j]));   // thread dep: MFMA can't hoist above waitcnt
    #pragma unroll
    for (int j = 0; j < 16; ++j) {
      bf16x8 b = *(const bf16x8*)(pb + (c * 16 + j) * 512);
      acc[j & 3] = __builtin_amdgcn_mfma_f32_32x32x16_bf16(CUR[j], b, acc[j & 3], 0, 0, 0);
    }
  }
}

__global__ void __launch_bounds__(256, 1) lstm_main(const short* __restrict__ xp,
    short* __restrict__ h0p, short* __restrict__ h1p,
    const short* __restrict__ wp0, const short* __restrict__ wp1,
    const float* __restrict__ bpack, const float* __restrict__ cin,
    float* __restrict__ out, unsigned* __restrict__ slots) {
  __shared__ short wlds[128 * 512];  // 128 KB weights -> 1 block/CU, 256 blocks co-resident
  const int blk = blockIdx.x;
  const int layer = blk >> 7;
  const int cu = blk & 127;
  const int tid = threadIdx.x;
  const int lane = tid & 63;
  const int wave = tid >> 6;

  const int nkc = layer ? 128 : 72;
  const short* wsrc = layer ? (wp1 + (size_t)cu * 128 * 512) : (wp0 + (size_t)cu * 72 * 512);
  for (int i = tid; i < nkc * 64; i += 256)
    ((int4*)wlds)[i] = ((const int4*)wsrc)[i];
  __syncthreads();

  const int col = lane & 31;
  const float bias = bpack[layer * 4096 + cu * 32 + col];
  const int uu = col & 7;
  const bool ewlane = (col < 8);
  const int gcol = cu * 8 + uu;
  const int hi4 = ((lane >> 5) << 2);

  float creg[16];
  #pragma unroll
  for (int r = 0; r < 16; ++r) {
    int grow = wave * 32 + (r & 3) + ((r >> 2) << 3) + hi4;
    creg[r] = ewlane ? cin[(size_t)layer * BB * HH + (size_t)grow * HH + gcol] : 0.f;
  }

  // producer store base (fragment-stream layout), excluding parity
  const int pst = (wave * 64 + (cu >> 1)) * 512 + ((cu & 1) << 8);  // +((cu&1)*32)*8

  for (int p = 0; p <= TT; ++p) {
    const bool active = layer ? (p >= 1) : (p < TT);
    if (active) {
      const int t = layer ? (p - 1) : p;
      f32x16 acc[4];
      #pragma unroll
      for (int r = 0; r < 16; ++r) {
        acc[0][r] = bias; acc[1][r] = 0.f; acc[2][r] = 0.f; acc[3][r] = 0.f;
      }
      const int parR = (p + 1) & 1;   // parity of h[t-1] inputs
      if (layer == 0) {
        gemm_plain<8>(acc, xp + ((size_t)(t * 4 + wave) * 8) * 512 + lane * 8,
                      wlds + lane * 8);
        gemm64_coh(acc, h0p + ((size_t)(parR * 4 + wave) * 64) * 512 + lane * 8,
                   wlds + 8 * 512 + lane * 8);
      } else {
        gemm64_coh(acc, h0p + ((size_t)(parR * 4 + wave) * 64) * 512 + lane * 8,
                   wlds + lane * 8);
        gemm64_coh(acc, h1p + ((size_t)(((p & 1)) * 4 + wave) * 64) * 512 + lane * 8,
                   wlds + 64 * 512 + lane * 8);
      }
      f32x16 accf = (acc[0] + acc[1]) + (acc[2] + acc[3]);
      short* hp = layer ? (h1p + (size_t)((p + 1) & 1) * HPAR)
                        : (h0p + (size_t)(p & 1) * HPAR);
      #pragma unroll
      for (int r = 0; r < 16; ++r) {
        float a0 = accf[r];
        float f_ = __shfl_xor(a0, 8);
        float g_ = __shfl_xor(a0, 16);
        float o_ = __shfl_xor(a0, 24);
        const int rloc = (r & 3) + ((r >> 2) << 3) + hi4;   // grow & 31
        const int grow = wave * 32 + rloc;
        float hnew = 0.f;
        if (ewlane) {
          float iv = fsig(a0), fv = fsig(f_), gv = ftanh(g_), ov = fsig(o_);
          float cnew = fv * creg[r] + iv * gv;
          creg[r] = cnew;
          hnew = ov * ftanh(cnew);
        }
        unsigned hb = (unsigned short)f2bf(hnew);
        unsigned pb2 = (unsigned)__shfl_xor((int)hb, 1);
        if (ewlane) {
          if (layer) out[(size_t)grow * TT * HH + (size_t)t * HH + gcol] = hnew;
          if (t == TT - 1) {
            out[BTH + (size_t)layer * BB * HH + (size_t)grow * HH + gcol] = hnew;          // h_f
            out[BTH + (size_t)(2 + layer) * BB * HH + (size_t)grow * HH + gcol] = creg[r]; // c_f
          }
          if (!(uu & 1)) {
            unsigned dw = hb | (pb2 << 16);
            // fragment-stream h store, write-through to coherent point (L3)
            __hip_atomic_store((unsigned*)(hp + pst + rloc * 8 + uu), dw,
                               __ATOMIC_RELAXED, __HIP_MEMORY_SCOPE_AGENT);
          }
        }
      }
    }
    if (p == TT) break;

    // ---- fence-free global barrier over 256 co-resident blocks ----
    __syncthreads();                 // each wave drains vmcnt(0): h stores ack'd at L3
    if (tid < 64) {
      if (tid == 0)
        __hip_atomic_store(&slots[blk], (unsigned)(p + 1),
                           __ATOMIC_RELAXED, __HIP_MEMORY_SCOPE_AGENT);
      const unsigned tgt = (unsigned)(p + 1);
      for (;;) {
        bool ok = true;
        #pragma unroll
        for (int j = 0; j < 4; ++j) {
          unsigned v = __hip_atomic_load(&slots[(tid << 2) + j],
                                         __ATOMIC_RELAXED, __HIP_MEMORY_SCOPE_AGENT);
          ok &= (v >= tgt);
        }
        if (__all(ok)) break;
        __builtin_amdgcn_s_sleep(2);
      }
      __atomic_signal_fence(__ATOMIC_SEQ_CST);
    }
    __syncthreads();
  }
}

// ---------------- host ----------------

extern "C" void kernel_launch(void* const* d_in, const int* in_sizes, int n_in,
                              void* d_out, int out_size, void* d_ws, size_t ws_size,
                              hipStream_t stream) {
  const float* x   = (const float*)d_in[0];
  const float* h   = (const float*)d_in[1];
  const float* c   = (const float*)d_in[2];
  const float* Wx0 = (const float*)d_in[3];
  const float* Wh0 = (const float*)d_in[4];
  const float* b0  = (const float*)d_in[5];
  const float* Wx1 = (const float*)d_in[6];
  const float* Wh1 = (const float*)d_in[7];
  const float* b1  = (const float*)d_in[8];
  float* out = (float*)d_out;

  char* ws = (char*)d_ws;
  short* xp  = (short*)ws;                          // 16,777,216 B : x fragment stream
  short* h0p = (short*)(ws + 16777216);             //    524,288 B : [2 par][frag stream]
  short* h1p = (short*)(ws + 17301504);             //    524,288 B
  short* wp0 = (short*)(ws + 17825792);             //  9,437,184 B
  short* wp1 = (short*)(ws + 27262976);             // 16,777,216 B
  float* bp  = (float*)(ws + 44040192);             //     32,768 B
  unsigned* slots = (unsigned*)(ws + 44072960);     //      1,024 B

  hipLaunchKernelGGL(conv_x,     dim3(2048), dim3(256), 0, stream, x, xp);
  hipLaunchKernelGGL(init_state, dim3(512),  dim3(256), 0, stream, h, h0p, h1p);
  hipLaunchKernelGGL(pack_w,     dim3(4096), dim3(256), 0, stream, Wx0, Wh0, Wx1, Wh1, wp0, wp1);
  hipLaunchKernelGGL(pack_b,     dim3(32),   dim3(256), 0, stream, b0, b1, bp, slots);

  hipLaunchKernelGGL(lstm_main, dim3(256), dim3(256), 0, stream,
                     xp, h0p, h1p, wp0, wp1, bp, c, out, slots);
}

// Round 5
// 6390.299 us; speedup vs baseline: 4.3927x; 1.2220x over previous
//
#include <hip/hip_runtime.h>

#define VV 128
#define HH 1024
#define BB 128
#define TT 512
#define G4 4096
#define BTH ((size_t)BB * TT * HH)
#define HPAR (4 * 64 * 512)   // shorts per parity of an h fragment-stream buffer (256 KB)

typedef __attribute__((ext_vector_type(8))) short bf16x8;
typedef __attribute__((ext_vector_type(16))) float f32x16;

__device__ __forceinline__ short f2bf(float f) {
  unsigned u = __float_as_uint(f);
  u = (u + 0x7fffu + ((u >> 16) & 1u)) >> 16;
  return (short)u;
}

__device__ __forceinline__ float fsig(float x) {
  x = fminf(fmaxf(x, -30.f), 30.f);
  float e = __expf(-x);
  return 1.f / (1.f + e);
}
__device__ __forceinline__ float ftanh(float x) {
  x = fminf(fmaxf(x, -15.f), 15.f);
  float e = __expf(-2.f * x);
  return (1.f - e) / (1.f + e);
}

// ---------------- pre-kernels ----------------

// x (B,T,V) f32 -> xp fragment stream [t][rb(4)][kc(8)][lane(64)][e(8)] bf16
__global__ void conv_x(const float* __restrict__ x, short* __restrict__ xp) {
  const int n = TT * 4 * 8 * 512;
  for (int i = blockIdx.x * blockDim.x + threadIdx.x; i < n; i += gridDim.x * blockDim.x) {
    int e = i & 7, lane = (i >> 3) & 63, kc = (i >> 9) & 7, rb = (i >> 12) & 3, t = i >> 14;
    int row = rb * 32 + (lane & 31);
    int v = kc * 16 + ((lane >> 5) << 3) + e;
    xp[i] = f2bf(x[((size_t)row * TT + t) * VV + v]);
  }
}

// h (L,B,H) -> parity-1 fragment-stream state buffers
__global__ void init_state(const float* __restrict__ h,
                           short* __restrict__ h0p, short* __restrict__ h1p) {
  const int n = 2 * HPAR;
  for (int i = blockIdx.x * blockDim.x + threadIdx.x; i < n; i += gridDim.x * blockDim.x) {
    int inner = i & (HPAR - 1);
    int l = i >> 17;
    int e = i & 7, lane = (i >> 3) & 63, kc = (i >> 9) & 63, rb = (i >> 15) & 3;
    int row = rb * 32 + (lane & 31);
    int j = kc * 16 + ((lane >> 5) << 3) + e;
    short hb = f2bf(h[((size_t)l * BB + row) * HH + j]);
    (l ? h1p : h0p)[HPAR + inner] = hb;
  }
}

// Pack weights into per-CU per-kc per-lane MFMA B-fragment streams (bf16).
__global__ void pack_w(const float* __restrict__ Wx0, const float* __restrict__ Wh0,
                       const float* __restrict__ Wx1, const float* __restrict__ Wh1,
                       short* __restrict__ wp0, short* __restrict__ wp1) {
  const int n0 = 128 * 72 * 512;
  const int n1 = 128 * 128 * 512;
  for (int i = blockIdx.x * blockDim.x + threadIdx.x; i < n0 + n1; i += gridDim.x * blockDim.x) {
    if (i < n0) {
      int cu = i / (72 * 512);
      int rem = i - cu * (72 * 512);
      int kc = rem >> 9, le = rem & 511;
      int lane = le >> 3, e = le & 7;
      int k = kc * 16 + ((lane >> 5) << 3) + e;
      int cl = lane & 31;
      int gcol = (cl >> 3) * HH + cu * 8 + (cl & 7);
      float f = (k < VV) ? Wx0[(size_t)k * G4 + gcol] : Wh0[(size_t)(k - VV) * G4 + gcol];
      wp0[i] = f2bf(f);
    } else {
      int j = i - n0;
      int cu = j >> 16;
      int rem = j & 65535;
      int kc = rem >> 9, le = rem & 511;
      int lane = le >> 3, e = le & 7;
      int k = kc * 16 + ((lane >> 5) << 3) + e;
      int cl = lane & 31;
      int gcol = (cl >> 3) * HH + cu * 8 + (cl & 7);
      float f = (k < HH) ? Wx1[(size_t)k * G4 + gcol] : Wh1[(size_t)(k - HH) * G4 + gcol];
      wp1[j] = f2bf(f);
    }
  }
}

__global__ void pack_b(const float* __restrict__ b0, const float* __restrict__ b1,
                       float* __restrict__ bp, unsigned* __restrict__ slots) {
  int i = blockIdx.x * blockDim.x + threadIdx.x;
  if (i < 2 * 128 * 32) {
    int l = i >> 12;
    int cu = (i >> 5) & 127;
    int cc = i & 31;
    const float* b = l ? b1 : b0;
    bp[i] = b[(cc >> 3) * HH + cu * 8 + (cc & 7)];
  }
  if (i < 512) slots[i] = 0u;   // slots[256] + gdone[256], re-armed every launch/replay
}

// ---------------- persistent LSTM kernel ----------------

// Deep-pipelined coherent h GEMM: 16-chunk groups, ring-3 (48 outstanding 1KB
// wave loads), counted vmcnt. NCH = 64 or 128. Chunks c<64 from pa0, else pa1.
template <int NCH>
__device__ __forceinline__ void hgemm(f32x16* acc, const short* pa0, const short* pa1,
                                      const short* __restrict__ pb) {
  constexpr int NG = NCH / 16;
  bf16x8 A[3][16];
#pragma unroll
  for (int g = 0; g < 3; ++g) {
#pragma unroll
    for (int j = 0; j < 16; ++j) {
      const int c = g * 16 + j;
      const short* ap = (c < 64) ? (pa0 + c * 512) : (pa1 + (c - 64) * 512);
      asm volatile("global_load_dwordx4 %0, %1, off sc0 sc1" : "=v"(A[g][j]) : "v"(ap));
    }
  }
#pragma unroll
  for (int g = 0; g < NG; ++g) {
    const int rem = NG - 1 - g;
    if (rem >= 2)      asm volatile("s_waitcnt vmcnt(32)" ::: "memory");
    else if (rem == 1) asm volatile("s_waitcnt vmcnt(16)" ::: "memory");
    else               asm volatile("s_waitcnt vmcnt(0)" ::: "memory");
#pragma unroll
    for (int j = 0; j < 16; ++j)
      asm volatile("" : "+v"(A[g % 3][j]));      // rule-18: pin MFMA below the wait
#pragma unroll
    for (int j = 0; j < 16; ++j) {
      const int c = g * 16 + j;
      bf16x8 b = *(const bf16x8*)(pb + c * 512);
      acc[j & 3] = __builtin_amdgcn_mfma_f32_32x32x16_bf16(A[g % 3][j], b, acc[j & 3], 0, 0, 0);
    }
    if (g + 3 < NG) {
#pragma unroll
      for (int j = 0; j < 16; ++j) {
        const int c = (g + 3) * 16 + j;
        const short* ap = (c < 64) ? (pa0 + c * 512) : (pa1 + (c - 64) * 512);
        asm volatile("global_load_dwordx4 %0, %1, off sc0 sc1"
                     : "=v"(A[(g + 3) % 3][j]) : "v"(ap));
      }
    }
  }
}

// x GEMM: 8 chunks, plain cacheable loads
__device__ __forceinline__ void xgemm(f32x16* acc, const short* __restrict__ pax,
                                      const short* __restrict__ pb) {
#pragma unroll
  for (int c = 0; c < 8; ++c) {
    bf16x8 a = *(const bf16x8*)(pax + c * 512);
    bf16x8 b = *(const bf16x8*)(pb + c * 512);
    acc[c & 3] = __builtin_amdgcn_mfma_f32_32x32x16_bf16(a, b, acc[c & 3], 0, 0, 0);
  }
}

__global__ void __launch_bounds__(256, 1) lstm_main(const short* __restrict__ xp,
    short* __restrict__ h0p, short* __restrict__ h1p,
    const short* __restrict__ wp0, const short* __restrict__ wp1,
    const float* __restrict__ bpack, const float* __restrict__ cin,
    float* __restrict__ out, unsigned* __restrict__ slots) {
  __shared__ short wlds[128 * 512];  // 128 KB weights -> 1 block/CU, 256 blocks co-resident
  unsigned* gdone = slots + 256;     // 8 group-done words, 128B apart
  const int blk = blockIdx.x;
  const int layer = blk >> 7;
  const int cu = blk & 127;
  const int tid = threadIdx.x;
  const int lane = tid & 63;
  const int wave = tid >> 6;

  const int nkc = layer ? 128 : 72;
  const short* wsrc = layer ? (wp1 + (size_t)cu * 128 * 512) : (wp0 + (size_t)cu * 72 * 512);
  for (int i = tid; i < nkc * 64; i += 256)
    ((int4*)wlds)[i] = ((const int4*)wsrc)[i];
  __syncthreads();

  const int col = lane & 31;
  const float bias = bpack[layer * 4096 + cu * 32 + col];
  const int uu = col & 7;
  const bool ewlane = (col < 8);
  const int gcol = cu * 8 + uu;
  const int hi4 = ((lane >> 5) << 2);

  float creg[16], hval[16];
#pragma unroll
  for (int r = 0; r < 16; ++r) {
    int grow = wave * 32 + (r & 3) + ((r >> 2) << 3) + hi4;
    creg[r] = ewlane ? cin[(size_t)layer * BB * HH + (size_t)grow * HH + gcol] : 0.f;
    hval[r] = 0.f;
  }

  const int pst = (wave * 64 + (cu >> 1)) * 512 + ((cu & 1) << 8);

  f32x16 acc[4];
  auto initacc = [&]() {
#pragma unroll
    for (int r = 0; r < 16; ++r) {
      acc[0][r] = bias; acc[1][r] = 0.f; acc[2][r] = 0.f; acc[3][r] = 0.f;
    }
  };

  if (layer == 0) {   // prologue: x GEMM for t=0 (independent of h)
    initacc();
    xgemm(acc, xp + ((size_t)(0 * 4 + wave) * 8) * 512 + lane * 8, wlds + lane * 8);
  }

  for (int p = 0; p <= TT; ++p) {
    // ---- hierarchical poll for epoch p ----
    if (p > 0) {
      const unsigned tgt = (unsigned)p;
      if ((blk & 31) == 0 && tid < 32) {        // relay: scan own group's slot line
        for (;;) {
          unsigned v = __hip_atomic_load(&slots[blk + tid],
                                         __ATOMIC_RELAXED, __HIP_MEMORY_SCOPE_AGENT);
          if (__all(v >= tgt)) break;
          __builtin_amdgcn_s_sleep(1);
        }
        if (tid == 0)
          __hip_atomic_store(&gdone[(blk >> 5) << 5], tgt,
                             __ATOMIC_RELAXED, __HIP_MEMORY_SCOPE_AGENT);
      }
      if (tid < 8) {                            // everyone: poll 8 group-done lines
        for (;;) {
          unsigned v = __hip_atomic_load(&gdone[tid << 5],
                                         __ATOMIC_RELAXED, __HIP_MEMORY_SCOPE_AGENT);
          if (__all(v >= tgt)) break;
          __builtin_amdgcn_s_sleep(1);
        }
      }
      __syncthreads();
    }

    const bool active = layer ? (p >= 1) : (p < TT);
    const int t = layer ? (p - 1) : p;
    if (active) {
      const int parR = (p + 1) & 1;
      if (layer == 0) {
        hgemm<64>(acc, h0p + ((size_t)(parR * 4 + wave) * 64) * 512 + lane * 8,
                  h0p, wlds + 8 * 512 + lane * 8);
      } else {
        initacc();
        hgemm<128>(acc, h0p + ((size_t)(parR * 4 + wave) * 64) * 512 + lane * 8,
                   h1p + ((size_t)((p & 1) * 4 + wave) * 64) * 512 + lane * 8,
                   wlds + lane * 8);
      }
      f32x16 accf = (acc[0] + acc[1]) + (acc[2] + acc[3]);
      short* hp = layer ? (h1p + (size_t)((p + 1) & 1) * HPAR)
                        : (h0p + (size_t)(p & 1) * HPAR);
#pragma unroll
      for (int r = 0; r < 16; ++r) {
        float a0 = accf[r];
        float nl = (col >= 16 && col < 24) ? ftanh(a0) : fsig(a0);  // one transcendental/lane
        float f_ = __shfl_xor(nl, 8);
        float g_ = __shfl_xor(nl, 16);
        float o_ = __shfl_xor(nl, 24);
        const int rloc = (r & 3) + ((r >> 2) << 3) + hi4;
        const int grow = wave * 32 + rloc;
        float hnew = 0.f;
        if (ewlane) {
          float cnew = f_ * creg[r] + nl * g_;
          creg[r] = cnew;
          hnew = o_ * ftanh(cnew);
          hval[r] = hnew;
        }
        unsigned hb = (unsigned short)f2bf(hnew);
        unsigned pb2 = (unsigned)__shfl_xor((int)hb, 1);
        if (ewlane) {
          if (t == TT - 1) {
            out[BTH + (size_t)layer * BB * HH + (size_t)grow * HH + gcol] = hnew;          // h_f
            out[BTH + (size_t)(2 + layer) * BB * HH + (size_t)grow * HH + gcol] = creg[r]; // c_f
          }
          if (!(uu & 1)) {
            unsigned dw = hb | (pb2 << 16);
            __hip_atomic_store((unsigned*)(hp + pst + rloc * 8 + uu), dw,
                               __ATOMIC_RELAXED, __HIP_MEMORY_SCOPE_AGENT);
          }
        }
      }
    }

    if (p == TT) {             // layer1's t=511: flush outs, then done (no arrive needed)
      if (layer && active && ewlane) {
#pragma unroll
        for (int r = 0; r < 16; ++r) {
          const int rloc = (r & 3) + ((r >> 2) << 3) + hi4;
          const int grow = wave * 32 + rloc;
          out[(size_t)grow * TT * HH + (size_t)t * HH + gcol] = hval[r];
        }
      }
      break;
    }

    // ---- arrive ----
    __syncthreads();           // all waves' sc1 h-stores drained to coherent point
    if (tid == 0)
      __hip_atomic_store(&slots[blk], (unsigned)(p + 1),
                         __ATOMIC_RELAXED, __HIP_MEMORY_SCOPE_AGENT);

    // ---- post-arrive overlap (off the inter-phase critical path) ----
    if (layer == 0) {
      if (p + 1 < TT) {
        initacc();
        xgemm(acc, xp + ((size_t)((p + 1) * 4 + wave) * 8) * 512 + lane * 8, wlds + lane * 8);
      }
    } else if (active && ewlane) {
#pragma unroll
      for (int r = 0; r < 16; ++r) {
        const int rloc = (r & 3) + ((r >> 2) << 3) + hi4;
        const int grow = wave * 32 + rloc;
        out[(size_t)grow * TT * HH + (size_t)t * HH + gcol] = hval[r];
      }
    }
  }
}

// ---------------- host ----------------

extern "C" void kernel_launch(void* const* d_in, const int* in_sizes, int n_in,
                              void* d_out, int out_size, void* d_ws, size_t ws_size,
                              hipStream_t stream) {
  const float* x   = (const float*)d_in[0];
  const float* h   = (const float*)d_in[1];
  const float* c   = (const float*)d_in[2];
  const float* Wx0 = (const float*)d_in[3];
  const float* Wh0 = (const float*)d_in[4];
  const float* b0  = (const float*)d_in[5];
  const float* Wx1 = (const float*)d_in[6];
  const float* Wh1 = (const float*)d_in[7];
  const float* b1  = (const float*)d_in[8];
  float* out = (float*)d_out;

  char* ws = (char*)d_ws;
  short* xp  = (short*)ws;                          // 16,777,216 B : x fragment stream
  short* h0p = (short*)(ws + 16777216);             //    524,288 B : [2 par][frag stream]
  short* h1p = (short*)(ws + 17301504);             //    524,288 B
  short* wp0 = (short*)(ws + 17825792);             //  9,437,184 B
  short* wp1 = (short*)(ws + 27262976);             // 16,777,216 B
  float* bp  = (float*)(ws + 44040192);             //     32,768 B
  unsigned* slots = (unsigned*)(ws + 44072960);     //  2,048 B : slots[256] + gdone[256]

  hipLaunchKernelGGL(conv_x,     dim3(2048), dim3(256), 0, stream, x, xp);
  hipLaunchKernelGGL(init_state, dim3(512),  dim3(256), 0, stream, h, h0p, h1p);
  hipLaunchKernelGGL(pack_w,     dim3(4096), dim3(256), 0, stream, Wx0, Wh0, Wx1, Wh1, wp0, wp1);
  hipLaunchKernelGGL(pack_b,     dim3(32),   dim3(256), 0, stream, b0, b1, bp, slots);

  hipLaunchKernelGGL(lstm_main, dim3(256), dim3(256), 0, stream,
                     xp, h0p, h1p, wp0, wp1, bp, c, out, slots);
}

// Round 6
// 6378.981 us; speedup vs baseline: 4.4005x; 1.0018x over previous
//
#include <hip/hip_runtime.h>

#define VV 128
#define HH 1024
#define BB 128
#define TT 512
#define G4 4096
#define BTH ((size_t)BB * TT * HH)
#define HPAR (4 * 64 * 512)   // shorts per h entry / parity (256 KB)
#define RING 256

typedef __attribute__((ext_vector_type(8))) short bf16x8;
typedef __attribute__((ext_vector_type(16))) float f32x16;

__device__ __forceinline__ short f2bf(float f) {
  unsigned u = __float_as_uint(f);
  u = (u + 0x7fffu + ((u >> 16) & 1u)) >> 16;
  return (short)u;
}

__device__ __forceinline__ float fsig(float x) {
  x = fminf(fmaxf(x, -30.f), 30.f);
  float e = __expf(-x);
  return 1.f / (1.f + e);
}
__device__ __forceinline__ float ftanh(float x) {
  x = fminf(fmaxf(x, -15.f), 15.f);
  float e = __expf(-2.f * x);
  return (1.f - e) / (1.f + e);
}

__device__ __forceinline__ unsigned eidx(int t) {   // ring entry for h[t], scrambled
  return ((unsigned)(t + 1) * 37u) & (RING - 1);
}

// ---------------- pre-kernels ----------------

__global__ void conv_x(const float* __restrict__ x, short* __restrict__ xp) {
  const int n = TT * 4 * 8 * 512;
  for (int i = blockIdx.x * blockDim.x + threadIdx.x; i < n; i += gridDim.x * blockDim.x) {
    int e = i & 7, lane = (i >> 3) & 63, kc = (i >> 9) & 7, rb = (i >> 12) & 3, t = i >> 14;
    int row = rb * 32 + (lane & 31);
    int v = kc * 16 + ((lane >> 5) << 3) + e;
    xp[i] = f2bf(x[((size_t)row * TT + t) * VV + v]);
  }
}

// h (L,B,H) -> fragment-stream entries at h0dst/h1dst (exact slot for h[-1])
__global__ void init_state(const float* __restrict__ h,
                           short* __restrict__ h0dst, short* __restrict__ h1dst) {
  const int n = 2 * HPAR;
  for (int i = blockIdx.x * blockDim.x + threadIdx.x; i < n; i += gridDim.x * blockDim.x) {
    int inner = i & (HPAR - 1);
    int l = i >> 17;
    int e = i & 7, lane = (i >> 3) & 63, kc = (i >> 9) & 63, rb = (i >> 15) & 3;
    int row = rb * 32 + (lane & 31);
    int j = kc * 16 + ((lane >> 5) << 3) + e;
    short hb = f2bf(h[((size_t)l * BB + row) * HH + j]);
    (l ? h1dst : h0dst)[inner] = hb;
  }
}

__global__ void pack_w(const float* __restrict__ Wx0, const float* __restrict__ Wh0,
                       const float* __restrict__ Wx1, const float* __restrict__ Wh1,
                       short* __restrict__ wp0, short* __restrict__ wp1) {
  const int n0 = 128 * 72 * 512;
  const int n1 = 128 * 128 * 512;
  for (int i = blockIdx.x * blockDim.x + threadIdx.x; i < n0 + n1; i += gridDim.x * blockDim.x) {
    if (i < n0) {
      int cu = i / (72 * 512);
      int rem = i - cu * (72 * 512);
      int kc = rem >> 9, le = rem & 511;
      int lane = le >> 3, e = le & 7;
      int k = kc * 16 + ((lane >> 5) << 3) + e;
      int cl = lane & 31;
      int gcol = (cl >> 3) * HH + cu * 8 + (cl & 7);
      float f = (k < VV) ? Wx0[(size_t)k * G4 + gcol] : Wh0[(size_t)(k - VV) * G4 + gcol];
      wp0[i] = f2bf(f);
    } else {
      int j = i - n0;
      int cu = j >> 16;
      int rem = j & 65535;
      int kc = rem >> 9, le = rem & 511;
      int lane = le >> 3, e = le & 7;
      int k = kc * 16 + ((lane >> 5) << 3) + e;
      int cl = lane & 31;
      int gcol = (cl >> 3) * HH + cu * 8 + (cl & 7);
      float f = (k < HH) ? Wx1[(size_t)k * G4 + gcol] : Wh1[(size_t)(k - HH) * G4 + gcol];
      wp1[j] = f2bf(f);
    }
  }
}

__global__ void pack_b(const float* __restrict__ b0, const float* __restrict__ b1,
                       float* __restrict__ bp, unsigned* __restrict__ slots) {
  int i = blockIdx.x * blockDim.x + threadIdx.x;
  if (i < 2 * 128 * 32) {
    int l = i >> 12;
    int cu = (i >> 5) & 127;
    int cc = i & 31;
    const float* b = l ? b1 : b0;
    bp[i] = b[(cc >> 3) * HH + cu * 8 + (cc & 7)];
  }
  if (i < 512) slots[i] = 0u;
}

// ---------------- persistent LSTM kernel ----------------

// Deep-pipelined h GEMM. COH=true: L3-direct (sc0 sc1). COH=false: L2-cached,
// L1-bypass (sc0) — valid only with never-reused (ring) addresses.
template <int NCH, bool COH>
__device__ __forceinline__ void hgemm(f32x16* acc, const short* pa0, const short* pa1,
                                      const short* __restrict__ pb) {
  constexpr int NG = NCH / 16;
  bf16x8 A[3][16];
#pragma unroll
  for (int g = 0; g < 3; ++g) {
#pragma unroll
    for (int j = 0; j < 16; ++j) {
      const int c = g * 16 + j;
      const short* ap = (c < 64) ? (pa0 + c * 512) : (pa1 + (c - 64) * 512);
      if constexpr (COH)
        asm volatile("global_load_dwordx4 %0, %1, off sc0 sc1" : "=v"(A[g][j]) : "v"(ap));
      else
        asm volatile("global_load_dwordx4 %0, %1, off sc0" : "=v"(A[g][j]) : "v"(ap));
    }
  }
#pragma unroll
  for (int g = 0; g < NG; ++g) {
    const int rem = NG - 1 - g;
    if (rem >= 2)      asm volatile("s_waitcnt vmcnt(32)" ::: "memory");
    else if (rem == 1) asm volatile("s_waitcnt vmcnt(16)" ::: "memory");
    else               asm volatile("s_waitcnt vmcnt(0)" ::: "memory");
#pragma unroll
    for (int j = 0; j < 16; ++j)
      asm volatile("" : "+v"(A[g % 3][j]));      // rule-18: pin MFMA below the wait
#pragma unroll
    for (int j = 0; j < 16; ++j) {
      const int c = g * 16 + j;
      bf16x8 b = *(const bf16x8*)(pb + c * 512);
      acc[j & 3] = __builtin_amdgcn_mfma_f32_32x32x16_bf16(A[g % 3][j], b, acc[j & 3], 0, 0, 0);
    }
    if (g + 3 < NG) {
#pragma unroll
      for (int j = 0; j < 16; ++j) {
        const int c = (g + 3) * 16 + j;
        const short* ap = (c < 64) ? (pa0 + c * 512) : (pa1 + (c - 64) * 512);
        if constexpr (COH)
          asm volatile("global_load_dwordx4 %0, %1, off sc0 sc1"
                       : "=v"(A[(g + 3) % 3][j]) : "v"(ap));
        else
          asm volatile("global_load_dwordx4 %0, %1, off sc0"
                       : "=v"(A[(g + 3) % 3][j]) : "v"(ap));
      }
    }
  }
}

__device__ __forceinline__ void xgemm(f32x16* acc, const short* __restrict__ pax,
                                      const short* __restrict__ pb) {
#pragma unroll
  for (int c = 0; c < 8; ++c) {
    bf16x8 a = *(const bf16x8*)(pax + c * 512);
    bf16x8 b = *(const bf16x8*)(pb + c * 512);
    acc[c & 3] = __builtin_amdgcn_mfma_f32_32x32x16_bf16(a, b, acc[c & 3], 0, 0, 0);
  }
}

// RINGM=true: h0b/h1b are 256-entry rings (plain-cacheable reads).
// RINGM=false: h0b/h1b are 2-parity buffers (sc0sc1 reads) — R5 fallback.
template <bool RINGM>
__global__ void __launch_bounds__(256, 1) lstm_main(const short* __restrict__ xp,
    short* __restrict__ h0b, short* __restrict__ h1b,
    const short* __restrict__ wp0, const short* __restrict__ wp1,
    const float* __restrict__ bpack, const float* __restrict__ cin,
    float* __restrict__ out, unsigned* __restrict__ slots) {
  __shared__ short wlds[128 * 512];
  unsigned* gdone = slots + 256;
  const int blk = blockIdx.x;
  const int layer = blk >> 7;
  const int cu = blk & 127;
  const int tid = threadIdx.x;
  const int lane = tid & 63;
  const int wave = tid >> 6;

  const int nkc = layer ? 128 : 72;
  const short* wsrc = layer ? (wp1 + (size_t)cu * 128 * 512) : (wp0 + (size_t)cu * 72 * 512);
  for (int i = tid; i < nkc * 64; i += 256)
    ((int4*)wlds)[i] = ((const int4*)wsrc)[i];
  __syncthreads();

  const int col = lane & 31;
  const float bias = bpack[layer * 4096 + cu * 32 + col];
  const int uu = col & 7;
  const bool ewlane = (col < 8);
  const int gcol = cu * 8 + uu;
  const int hi4 = ((lane >> 5) << 2);

  float creg[16], hval[16];
#pragma unroll
  for (int r = 0; r < 16; ++r) {
    int grow = wave * 32 + (r & 3) + ((r >> 2) << 3) + hi4;
    creg[r] = ewlane ? cin[(size_t)layer * BB * HH + (size_t)grow * HH + gcol] : 0.f;
    hval[r] = 0.f;
  }

  const int pst = (wave * 64 + (cu >> 1)) * 512 + ((cu & 1) << 8);
  const int wv64 = wave * 64 * 512 + lane * 8;   // wave slice inside an entry

  f32x16 acc[4];
  auto initacc = [&]() {
#pragma unroll
    for (int r = 0; r < 16; ++r) {
      acc[0][r] = bias; acc[1][r] = 0.f; acc[2][r] = 0.f; acc[3][r] = 0.f;
    }
  };

  if (layer == 0) {
    initacc();
    xgemm(acc, xp + ((size_t)(0 * 4 + wave) * 8) * 512 + lane * 8, wlds + lane * 8);
  }

  for (int p = 0; p <= TT; ++p) {
    if (p > 0) {   // ---- hierarchical poll ----
      const unsigned tgt = (unsigned)p;
      if ((blk & 31) == 0 && tid < 32) {
        for (;;) {
          unsigned v = __hip_atomic_load(&slots[blk + tid],
                                         __ATOMIC_RELAXED, __HIP_MEMORY_SCOPE_AGENT);
          if (__all(v >= tgt)) break;
          __builtin_amdgcn_s_sleep(1);
        }
        if (tid == 0)
          __hip_atomic_store(&gdone[(blk >> 5) << 5], tgt,
                             __ATOMIC_RELAXED, __HIP_MEMORY_SCOPE_AGENT);
      }
      if (tid < 8) {
        for (;;) {
          unsigned v = __hip_atomic_load(&gdone[tid << 5],
                                         __ATOMIC_RELAXED, __HIP_MEMORY_SCOPE_AGENT);
          if (__all(v >= tgt)) break;
          __builtin_amdgcn_s_sleep(1);
        }
      }
      __syncthreads();
    }

    const bool active = layer ? (p >= 1) : (p < TT);
    const int t = layer ? (p - 1) : p;
    if (active) {
      const short *ra0, *ra1;
      if constexpr (RINGM) {
        ra0 = h0b + (size_t)eidx(p - 1) * HPAR + wv64;            // h0[t-1] / h0[t]
        ra1 = h1b + (size_t)eidx(p - 2) * HPAR + wv64;            // h1[t-2+1]=h1[t-1]
      } else {
        const int parR = (p + 1) & 1;
        ra0 = h0b + (size_t)parR * HPAR + wv64;
        ra1 = h1b + (size_t)(p & 1) * HPAR + wv64;
      }
      if (layer == 0) {
        hgemm<64, !RINGM>(acc, ra0, ra0, wlds + 8 * 512 + lane * 8);
      } else {
        initacc();
        hgemm<128, !RINGM>(acc, ra0, ra1, wlds + lane * 8);
      }
      f32x16 accf = (acc[0] + acc[1]) + (acc[2] + acc[3]);
      short* hp;
      if constexpr (RINGM)
        hp = layer ? (h1b + (size_t)eidx(p - 1) * HPAR)           // write h1[t]
                   : (h0b + (size_t)eidx(p) * HPAR);              // write h0[t]
      else
        hp = layer ? (h1b + (size_t)((p + 1) & 1) * HPAR)
                   : (h0b + (size_t)(p & 1) * HPAR);
#pragma unroll
      for (int r = 0; r < 16; ++r) {
        float a0 = accf[r];
        float nl = (col >= 16 && col < 24) ? ftanh(a0) : fsig(a0);
        float f_ = __shfl_xor(nl, 8);
        float g_ = __shfl_xor(nl, 16);
        float o_ = __shfl_xor(nl, 24);
        const int rloc = (r & 3) + ((r >> 2) << 3) + hi4;
        const int grow = wave * 32 + rloc;
        float hnew = 0.f;
        if (ewlane) {
          float cnew = f_ * creg[r] + nl * g_;
          creg[r] = cnew;
          hnew = o_ * ftanh(cnew);
          hval[r] = hnew;
        }
        unsigned hb = (unsigned short)f2bf(hnew);
        unsigned pb2 = (unsigned)__shfl_xor((int)hb, 1);
        if (ewlane) {
          if (t == TT - 1) {
            out[BTH + (size_t)layer * BB * HH + (size_t)grow * HH + gcol] = hnew;
            out[BTH + (size_t)(2 + layer) * BB * HH + (size_t)grow * HH + gcol] = creg[r];
          }
          if (!(uu & 1)) {
            unsigned dw = hb | (pb2 << 16);
            __hip_atomic_store((unsigned*)(hp + pst + rloc * 8 + uu), dw,
                               __ATOMIC_RELAXED, __HIP_MEMORY_SCOPE_AGENT);
          }
        }
      }
    }

    if (p == TT) {
      if (layer && active && ewlane) {
#pragma unroll
        for (int r = 0; r < 16; ++r) {
          const int rloc = (r & 3) + ((r >> 2) << 3) + hi4;
          const int grow = wave * 32 + rloc;
          out[(size_t)grow * TT * HH + (size_t)t * HH + gcol] = hval[r];
        }
      }
      break;
    }

    __syncthreads();
    if (tid == 0)
      __hip_atomic_store(&slots[blk], (unsigned)(p + 1),
                         __ATOMIC_RELAXED, __HIP_MEMORY_SCOPE_AGENT);

    if (layer == 0) {
      if (p + 1 < TT) {
        initacc();
        xgemm(acc, xp + ((size_t)((p + 1) * 4 + wave) * 8) * 512 + lane * 8, wlds + lane * 8);
      }
    } else if (active && ewlane) {
#pragma unroll
      for (int r = 0; r < 16; ++r) {
        const int rloc = (r & 3) + ((r >> 2) << 3) + hi4;
        const int grow = wave * 32 + rloc;
        out[(size_t)grow * TT * HH + (size_t)t * HH + gcol] = hval[r];
      }
    }
  }
}

// ---------------- host ----------------

extern "C" void kernel_launch(void* const* d_in, const int* in_sizes, int n_in,
                              void* d_out, int out_size, void* d_ws, size_t ws_size,
                              hipStream_t stream) {
  const float* x   = (const float*)d_in[0];
  const float* h   = (const float*)d_in[1];
  const float* c   = (const float*)d_in[2];
  const float* Wx0 = (const float*)d_in[3];
  const float* Wh0 = (const float*)d_in[4];
  const float* b0  = (const float*)d_in[5];
  const float* Wx1 = (const float*)d_in[6];
  const float* Wh1 = (const float*)d_in[7];
  const float* b1  = (const float*)d_in[8];
  float* out = (float*)d_out;

  char* ws = (char*)d_ws;
  short* xp  = (short*)ws;                          // 16,777,216
  short* wp0 = (short*)(ws + 16777216);             //  9,437,184
  short* wp1 = (short*)(ws + 26214400);             // 16,777,216
  float* bp  = (float*)(ws + 42991616);             //     32,768
  unsigned* slots = (unsigned*)(ws + 43024384);     //      2,048
  short* h0p = (short*)(ws + 43026432);             //    524,288 (fallback, 2 parities)
  short* h1p = (short*)(ws + 43550720);             //    524,288
  short* h0r = (short*)(ws + 44075008);             // 67,108,864 (ring, 256 entries)
  short* h1r = (short*)(ws + 111183872);            // 67,108,864
  const size_t need_ring = 178292736;

  const bool ring = (ws_size >= need_ring);
  short* h0 = ring ? h0r : h0p;
  short* h1 = ring ? h1r : h1p;
  // h[-1] destination: ring entry eidx(-1)=0, or parity 1 for fallback
  short* h0ini = ring ? h0r : (h0p + HPAR);
  short* h1ini = ring ? h1r : (h1p + HPAR);

  hipLaunchKernelGGL(conv_x,     dim3(2048), dim3(256), 0, stream, x, xp);
  hipLaunchKernelGGL(init_state, dim3(512),  dim3(256), 0, stream, h, h0ini, h1ini);
  hipLaunchKernelGGL(pack_w,     dim3(4096), dim3(256), 0, stream, Wx0, Wh0, Wx1, Wh1, wp0, wp1);
  hipLaunchKernelGGL(pack_b,     dim3(32),   dim3(256), 0, stream, b0, b1, bp, slots);

  if (ring)
    hipLaunchKernelGGL((lstm_main<true>), dim3(256), dim3(256), 0, stream,
                       xp, h0, h1, wp0, wp1, bp, c, out, slots);
  else
    hipLaunchKernelGGL((lstm_main<false>), dim3(256), dim3(256), 0, stream,
                       xp, h0, h1, wp0, wp1, bp, c, out, slots);
}